// Round 1
// baseline (3994.906 us; speedup 1.0000x reference)
//
#include <hip/hip_runtime.h>

#define B 4
#define C 512
#define CI 256
#define NN 4096
#define SCALE_PAM 0.04419417382415922f  // 1/sqrt(512)
#define SCALE_CAM (1.0f/64.0f)          // 1/sqrt(4096)

__device__ __forceinline__ float4 ld4(const float* p) { return *(const float4*)p; }

__device__ __forceinline__ void fma44(float (&acc)[4][4], const float4 a, const float4 b) {
  acc[0][0] = fmaf(a.x, b.x, acc[0][0]);
  acc[0][1] = fmaf(a.x, b.y, acc[0][1]);
  acc[0][2] = fmaf(a.x, b.z, acc[0][2]);
  acc[0][3] = fmaf(a.x, b.w, acc[0][3]);
  acc[1][0] = fmaf(a.y, b.x, acc[1][0]);
  acc[1][1] = fmaf(a.y, b.y, acc[1][1]);
  acc[1][2] = fmaf(a.y, b.z, acc[1][2]);
  acc[1][3] = fmaf(a.y, b.w, acc[1][3]);
  acc[2][0] = fmaf(a.z, b.x, acc[2][0]);
  acc[2][1] = fmaf(a.z, b.y, acc[2][1]);
  acc[2][2] = fmaf(a.z, b.z, acc[2][2]);
  acc[2][3] = fmaf(a.z, b.w, acc[2][3]);
  acc[3][0] = fmaf(a.w, b.x, acc[3][0]);
  acc[3][1] = fmaf(a.w, b.y, acc[3][1]);
  acc[3][2] = fmaf(a.w, b.z, acc[3][2]);
  acc[3][3] = fmaf(a.w, b.w, acc[3][3]);
}

// ---------------------------------------------------------------------------
// K1: fused QKV GEMM.  y[b][o][n] = sum_c W[o][c] x[b][c][n] + bias[o]
// o in [0,1024): [0,256)->q, [256,512)->k, [512,1024)->v
// grid (32 n-tiles, 32 o-tiles, B), block 256. tile 32o x 128n, 4x4/thread.
// ---------------------------------------------------------------------------
__global__ __launch_bounds__(256) void k_qkv(
    const float* __restrict__ x,
    const float* __restrict__ wq, const float* __restrict__ bq,
    const float* __restrict__ wk, const float* __restrict__ bk,
    const float* __restrict__ wv, const float* __restrict__ bv,
    float* __restrict__ q, float* __restrict__ k, float* __restrict__ v) {
  const int b = blockIdx.z;
  const int o0 = blockIdx.y * 32;
  const int n0 = blockIdx.x * 128;
  const int t = threadIdx.x;

  const float* W; const float* bias; float* Y; int orow; int R;
  if (o0 < 256)      { W = wq; bias = bq; Y = q; orow = o0;       R = CI; }
  else if (o0 < 512) { W = wk; bias = bk; Y = k; orow = o0 - 256; R = CI; }
  else               { W = wv; bias = bv; Y = v; orow = o0 - 512; R = C;  }

  __shared__ float wt[32][32];    // [c][o] transposed
  __shared__ float xt[32][128];   // [c][n]
  float acc[4][4] = {};
  const int to = (t >> 5) * 4;    // o offset within tile
  const int tn = (t & 31) * 4;    // n offset within tile
  const float* xb = x + ((size_t)b * C) * NN + n0;

  for (int c0 = 0; c0 < C; c0 += 32) {
    {
      int o = t >> 3;
      int c4 = (t & 7) * 4;
      float4 w4 = ld4(&W[(size_t)(orow + o) * C + c0 + c4]);
      wt[c4 + 0][o] = w4.x; wt[c4 + 1][o] = w4.y;
      wt[c4 + 2][o] = w4.z; wt[c4 + 3][o] = w4.w;
    }
    {
      int id = t;
#pragma unroll
      for (int r = 0; r < 4; ++r) {
        int cc = id >> 5, nf = (id & 31) * 4;
        *(float4*)&xt[cc][nf] = ld4(&xb[(size_t)(c0 + cc) * NN + nf]);
        id += 256;
      }
    }
    __syncthreads();
#pragma unroll 8
    for (int cc = 0; cc < 32; ++cc) {
      float4 w4 = *(float4*)&wt[cc][to];
      float4 x4 = *(float4*)&xt[cc][tn];
      fma44(acc, w4, x4);
    }
    __syncthreads();
  }
#pragma unroll
  for (int i = 0; i < 4; ++i) {
    int oi = orow + to + i;
    float bv_ = bias[oi];
    float4 y4 = { acc[i][0] + bv_, acc[i][1] + bv_, acc[i][2] + bv_, acc[i][3] + bv_ };
    *(float4*)&Y[((size_t)b * R + oi) * NN + n0 + tn] = y4;
  }
}

// ---------------------------------------------------------------------------
// K2: fused PAM: flash-style online softmax over j, accumulate V, epilogue
// sa = tanh(gamma*pam + x).  grid (128 i-tiles, B), block 256.
// Phase A: S[32i][64j] (K=256); Phase B: acc[512c][32i] += V P^T.
// ---------------------------------------------------------------------------
__global__ __launch_bounds__(256) void k_pam(
    const float* __restrict__ q, const float* __restrict__ k,
    const float* __restrict__ v, const float* __restrict__ x,
    const float* __restrict__ gamma_pam, float* __restrict__ sa) {
  const int b = blockIdx.y;
  const int i0 = blockIdx.x * 32;
  const int t = threadIdx.x;
  __shared__ float qt[32][32];    // [c][i]
  __shared__ float kt[32][64];    // [c][j]
  __shared__ float pt[32][65];    // [i][j] (+1 pad: column reads conflict-free)
  __shared__ float vt[64][64];    // [j][c] transposed chunk
  __shared__ float alpha_s[32];
  __shared__ float l_s[32];

  float accv[64];
#pragma unroll
  for (int r = 0; r < 64; ++r) accv[r] = 0.f;
  const int ia = t >> 3, ja = (t & 7) * 8;   // phase A: row ia, 8 j's
  const int ib = t & 31, cgrp = t >> 5;      // phase B: row ib, c-group
  float m_run = -1e30f, l_run = 0.f;
  const float* qb = q + (size_t)b * CI * NN;
  const float* kb = k + (size_t)b * CI * NN;
  const float* vb = v + (size_t)b * C * NN;

  for (int j0 = 0; j0 < NN; j0 += 64) {
    float s8[8];
#pragma unroll
    for (int r = 0; r < 8; ++r) s8[r] = 0.f;
    for (int c0 = 0; c0 < CI; c0 += 32) {
      {
        int cc = t >> 3, i4 = (t & 7) * 4;
        *(float4*)&qt[cc][i4] = ld4(&qb[(size_t)(c0 + cc) * NN + i0 + i4]);
      }
      {
        int id = t;
#pragma unroll
        for (int r = 0; r < 2; ++r) {
          int cc = id >> 4, j4 = (id & 15) * 4;
          *(float4*)&kt[cc][j4] = ld4(&kb[(size_t)(c0 + cc) * NN + j0 + j4]);
          id += 256;
        }
      }
      __syncthreads();
#pragma unroll 8
      for (int cc = 0; cc < 32; ++cc) {
        float qv = qt[cc][ia];
        float4 k40 = *(float4*)&kt[cc][ja];
        float4 k41 = *(float4*)&kt[cc][ja + 4];
        s8[0] = fmaf(qv, k40.x, s8[0]);
        s8[1] = fmaf(qv, k40.y, s8[1]);
        s8[2] = fmaf(qv, k40.z, s8[2]);
        s8[3] = fmaf(qv, k40.w, s8[3]);
        s8[4] = fmaf(qv, k41.x, s8[4]);
        s8[5] = fmaf(qv, k41.y, s8[5]);
        s8[6] = fmaf(qv, k41.z, s8[6]);
        s8[7] = fmaf(qv, k41.w, s8[7]);
      }
      __syncthreads();
    }
#pragma unroll
    for (int r = 0; r < 8; ++r) s8[r] *= SCALE_PAM;
    float mx = s8[0];
#pragma unroll
    for (int r = 1; r < 8; ++r) mx = fmaxf(mx, s8[r]);
    mx = fmaxf(mx, __shfl_xor(mx, 1));
    mx = fmaxf(mx, __shfl_xor(mx, 2));
    mx = fmaxf(mx, __shfl_xor(mx, 4));
    float m_new = fmaxf(m_run, mx);
    float psum = 0.f;
#pragma unroll
    for (int r = 0; r < 8; ++r) { s8[r] = __expf(s8[r] - m_new); psum += s8[r]; }
    psum += __shfl_xor(psum, 1);
    psum += __shfl_xor(psum, 2);
    psum += __shfl_xor(psum, 4);
    float alpha = __expf(m_run - m_new);
    l_run = l_run * alpha + psum;
    m_run = m_new;
#pragma unroll
    for (int r = 0; r < 8; ++r) pt[ia][ja + r] = s8[r];
    if ((t & 7) == 0) alpha_s[ia] = alpha;
    __syncthreads();

    float al = alpha_s[ib];
#pragma unroll
    for (int r = 0; r < 64; ++r) accv[r] *= al;
    for (int ch = 0; ch < 8; ++ch) {
      int id = t;
#pragma unroll
      for (int r = 0; r < 4; ++r) {
        int cc = id >> 4, j4 = (id & 15) * 4;
        float4 v4 = ld4(&vb[(size_t)(ch * 64 + cc) * NN + j0 + j4]);
        vt[j4 + 0][cc] = v4.x; vt[j4 + 1][cc] = v4.y;
        vt[j4 + 2][cc] = v4.z; vt[j4 + 3][cc] = v4.w;
        id += 256;
      }
      __syncthreads();
#pragma unroll 8
      for (int jj = 0; jj < 64; ++jj) {
        float pv = pt[ib][jj];
        float4 v40 = *(float4*)&vt[jj][cgrp * 8];
        float4 v41 = *(float4*)&vt[jj][cgrp * 8 + 4];
        accv[ch * 8 + 0] = fmaf(v40.x, pv, accv[ch * 8 + 0]);
        accv[ch * 8 + 1] = fmaf(v40.y, pv, accv[ch * 8 + 1]);
        accv[ch * 8 + 2] = fmaf(v40.z, pv, accv[ch * 8 + 2]);
        accv[ch * 8 + 3] = fmaf(v40.w, pv, accv[ch * 8 + 3]);
        accv[ch * 8 + 4] = fmaf(v41.x, pv, accv[ch * 8 + 4]);
        accv[ch * 8 + 5] = fmaf(v41.y, pv, accv[ch * 8 + 5]);
        accv[ch * 8 + 6] = fmaf(v41.z, pv, accv[ch * 8 + 6]);
        accv[ch * 8 + 7] = fmaf(v41.w, pv, accv[ch * 8 + 7]);
      }
      __syncthreads();
    }
  }
  if ((t & 7) == 0) l_s[ia] = l_run;
  __syncthreads();
  const float inv = (1.0f / (float)NN) / l_s[ib];
  const float gp = gamma_pam[0];
  const float* xb = x + (size_t)b * C * NN;
  float* sab = sa + (size_t)b * C * NN;
#pragma unroll
  for (int ch = 0; ch < 8; ++ch) {
#pragma unroll
    for (int cl = 0; cl < 8; ++cl) {
      int cc = ch * 64 + cgrp * 8 + cl;
      size_t idx = (size_t)cc * NN + i0 + ib;
      sab[idx] = tanhf(fmaf(gp, accv[ch * 8 + cl] * inv, xb[idx]));
    }
  }
}

// ---------------------------------------------------------------------------
// K3: CAM gram: e_part[ks][b][c][d] = SCALE_CAM * sum_{n in ks-range} sa_c sa_d
// grid (64 tiles, 4 ksplit, B), block 256. tile 64x64, 4x4/thread.
// ---------------------------------------------------------------------------
__global__ __launch_bounds__(256) void k_cam_e(
    const float* __restrict__ sa, float* __restrict__ e_part) {
  const int b = blockIdx.z, ks = blockIdx.y;
  const int ct = blockIdx.x & 7, dt = blockIdx.x >> 3;
  const int t = threadIdx.x;
  const int c0 = ct * 64, d0 = dt * 64;
  __shared__ float At[64][64];  // [n][c]
  __shared__ float Bt[64][64];  // [n][d]
  float acc[4][4] = {};
  const int tc = (t & 15) * 4, td = (t >> 4) * 4;
  const float* sb = sa + (size_t)b * C * NN;

  for (int n0 = ks * 1024; n0 < ks * 1024 + 1024; n0 += 64) {
    {
      int id = t;
#pragma unroll
      for (int r = 0; r < 4; ++r) {
        int cc = id >> 4, j4 = (id & 15) * 4;
        float4 a4 = ld4(&sb[(size_t)(c0 + cc) * NN + n0 + j4]);
        At[j4 + 0][cc] = a4.x; At[j4 + 1][cc] = a4.y;
        At[j4 + 2][cc] = a4.z; At[j4 + 3][cc] = a4.w;
        id += 256;
      }
    }
    {
      int id = t;
#pragma unroll
      for (int r = 0; r < 4; ++r) {
        int cc = id >> 4, j4 = (id & 15) * 4;
        float4 a4 = ld4(&sb[(size_t)(d0 + cc) * NN + n0 + j4]);
        Bt[j4 + 0][cc] = a4.x; Bt[j4 + 1][cc] = a4.y;
        Bt[j4 + 2][cc] = a4.z; Bt[j4 + 3][cc] = a4.w;
        id += 256;
      }
    }
    __syncthreads();
#pragma unroll 8
    for (int nn = 0; nn < 64; ++nn) {
      float4 a4 = *(float4*)&At[nn][tc];
      float4 b4 = *(float4*)&Bt[nn][td];
      fma44(acc, a4, b4);
    }
    __syncthreads();
  }
  float* ep = e_part + ((size_t)ks * B + b) * C * C;
#pragma unroll
  for (int i = 0; i < 4; ++i) {
    float4 r4 = { acc[i][0] * SCALE_CAM, acc[i][1] * SCALE_CAM,
                  acc[i][2] * SCALE_CAM, acc[i][3] * SCALE_CAM };
    *(float4*)&ep[(size_t)(c0 + tc + i) * C + d0 + td] = r4;
  }
}

// ---------------------------------------------------------------------------
// K4: CAM softmax.  energy_new = rowmax(e) - e; softmax(energy_new)/C
//   == exp(min_e - e) / sum(exp(min_e - e)) / C   (rowmax shift cancels)
// grid (C, B), block 64 (1 wave). Sums the 4 k-split parts.
// ---------------------------------------------------------------------------
__global__ __launch_bounds__(64) void k_cam_softmax(
    const float* __restrict__ e_part, float* __restrict__ attn) {
  const int c = blockIdx.x, b = blockIdx.y;
  const int lane = threadIdx.x;
  size_t roff = ((size_t)b * C + c) * C;
  float vals[8];
#pragma unroll
  for (int r = 0; r < 8; ++r) {
    int d = lane + r * 64;
    float s = 0.f;
#pragma unroll
    for (int p = 0; p < 4; ++p) s += e_part[(size_t)p * B * C * C + roff + d];
    vals[r] = s;
  }
  float mn = vals[0];
#pragma unroll
  for (int r = 1; r < 8; ++r) mn = fminf(mn, vals[r]);
#pragma unroll
  for (int m = 32; m >= 1; m >>= 1) mn = fminf(mn, __shfl_xor(mn, m));
  float sum = 0.f;
#pragma unroll
  for (int r = 0; r < 8; ++r) { vals[r] = __expf(mn - vals[r]); sum += vals[r]; }
#pragma unroll
  for (int m = 32; m >= 1; m >>= 1) sum += __shfl_xor(sum, m);
  float sc = (1.0f / (float)C) / sum;
#pragma unroll
  for (int r = 0; r < 8; ++r) attn[roff + lane + r * 64] = vals[r] * sc;
}

// ---------------------------------------------------------------------------
// K5: CAM apply + residual: out = gamma_cam * (attn @ sa) + sa
// grid (32 n-tiles, 16 c-tiles, B), block 256. tile 32c x 128n.
// ---------------------------------------------------------------------------
__global__ __launch_bounds__(256) void k_cam_out(
    const float* __restrict__ attn, const float* __restrict__ sa,
    const float* __restrict__ gamma_cam, float* __restrict__ out) {
  const int b = blockIdx.z;
  const int c0 = blockIdx.y * 32;
  const int n0 = blockIdx.x * 128;
  const int t = threadIdx.x;
  __shared__ float at[32][32];   // [d][c] transposed
  __shared__ float st[32][128];  // [d][n]
  float acc[4][4] = {};
  const int tc = (t >> 5) * 4;
  const int tn = (t & 31) * 4;
  const float* ab = attn + (size_t)b * C * C;
  const float* sb = sa + (size_t)b * C * NN;

  for (int d0 = 0; d0 < C; d0 += 32) {
    {
      int cc = t >> 3;
      int d4 = (t & 7) * 4;
      float4 a4 = ld4(&ab[(size_t)(c0 + cc) * C + d0 + d4]);
      at[d4 + 0][cc] = a4.x; at[d4 + 1][cc] = a4.y;
      at[d4 + 2][cc] = a4.z; at[d4 + 3][cc] = a4.w;
    }
    {
      int id = t;
#pragma unroll
      for (int r = 0; r < 4; ++r) {
        int dd = id >> 5, nf = (id & 31) * 4;
        *(float4*)&st[dd][nf] = ld4(&sb[(size_t)(d0 + dd) * NN + n0 + nf]);
        id += 256;
      }
    }
    __syncthreads();
#pragma unroll 8
    for (int dd = 0; dd < 32; ++dd) {
      float4 a4 = *(float4*)&at[dd][tc];
      float4 s4 = *(float4*)&st[dd][tn];
      fma44(acc, a4, s4);
    }
    __syncthreads();
  }
  const float gc = gamma_cam[0];
#pragma unroll
  for (int i = 0; i < 4; ++i) {
    int cc = c0 + tc + i;
    float4 s4 = ld4(&sb[(size_t)cc * NN + n0 + tn]);
    float4 o4 = { fmaf(gc, acc[i][0], s4.x), fmaf(gc, acc[i][1], s4.y),
                  fmaf(gc, acc[i][2], s4.z), fmaf(gc, acc[i][3], s4.w) };
    *(float4*)&out[((size_t)b * C + cc) * NN + n0 + tn] = o4;
  }
}

// ---------------------------------------------------------------------------
extern "C" void kernel_launch(void* const* d_in, const int* in_sizes, int n_in,
                              void* d_out, int out_size, void* d_ws, size_t ws_size,
                              hipStream_t stream) {
  const float* x  = (const float*)d_in[0];
  const float* wq = (const float*)d_in[1];
  const float* bq = (const float*)d_in[2];
  const float* wk = (const float*)d_in[3];
  const float* bk = (const float*)d_in[4];
  const float* wv = (const float*)d_in[5];
  const float* bv = (const float*)d_in[6];
  const float* gp = (const float*)d_in[7];
  const float* gc = (const float*)d_in[8];
  float* out = (float*)d_out;

  float* ws = (float*)d_ws;
  float* q      = ws;                               // B*CI*NN = 4.19M floats
  float* k      = q + (size_t)B * CI * NN;          // 4.19M
  float* v      = k + (size_t)B * CI * NN;          // B*C*NN = 8.39M
  float* sa     = v + (size_t)B * C * NN;           // 8.39M
  float* e_part = sa + (size_t)B * C * NN;          // 4*B*C*C = 4.19M
  float* attn   = e_part + (size_t)4 * B * C * C;   // B*C*C = 1.05M

  k_qkv<<<dim3(32, 32, B), 256, 0, stream>>>(x, wq, bq, wk, bk, wv, bv, q, k, v);
  k_pam<<<dim3(128, B), 256, 0, stream>>>(q, k, v, x, gp, sa);
  k_cam_e<<<dim3(64, 4, B), 256, 0, stream>>>(sa, e_part);
  k_cam_softmax<<<dim3(C, B), 64, 0, stream>>>(e_part, attn);
  k_cam_out<<<dim3(32, 16, B), 256, 0, stream>>>(attn, sa, gc, out);
}

// Round 2
// 611.868 us; speedup vs baseline: 6.5290x; 6.5290x over previous
//
#include <hip/hip_runtime.h>

#define B_ 4
#define C_ 512
#define CI_ 256
#define N_ 4096
#define SCALE_PAM 0.04419417382415922f  // 1/sqrt(512)
#define SCALE_CAM (1.0f/64.0f)          // 1/sqrt(4096)
#define SHIFT_PAM 8.0f                  // fixed softmax shift (logits bounded ~|8|)

typedef float v4f __attribute__((ext_vector_type(4)));
typedef short v8s __attribute__((ext_vector_type(8)));

__device__ __forceinline__ unsigned short f2bf(float f) {
  unsigned int u = __float_as_uint(f);
  u = (u + 0x7FFFu + ((u >> 16) & 1u)) >> 16;
  return (unsigned short)u;
}

__device__ __forceinline__ v8s ld8(const unsigned short* p) {
  v8s r; *(int4*)&r = *(const int4*)p; return r;
}

__device__ __forceinline__ v4f mfma16(v8s a, v8s b, v4f c) {
  return __builtin_amdgcn_mfma_f32_16x16x32_bf16(a, b, c, 0, 0, 0);
}

// ---------------------------------------------------------------------------
// K0a: transpose+convert x fp32 [b][c][n] -> xT bf16 [b][n][c]. 64x64 tiles.
// ---------------------------------------------------------------------------
__global__ __launch_bounds__(256) void k_xT(const float* __restrict__ x,
                                            unsigned short* __restrict__ xT) {
  const int b = blockIdx.z, c0 = blockIdx.y * 64, n0 = blockIdx.x * 64;
  const int t = threadIdx.x;
  __shared__ unsigned short ts[64 * 72];  // [n][c]
  const int cl = t >> 2, nseg = (t & 3) * 16;
  const float* xr = x + ((size_t)b * C_ + c0 + cl) * N_ + n0 + nseg;
#pragma unroll
  for (int k = 0; k < 4; ++k) {
    float4 f = *(const float4*)(xr + k * 4);
    ts[(nseg + k * 4 + 0) * 72 + cl] = f2bf(f.x);
    ts[(nseg + k * 4 + 1) * 72 + cl] = f2bf(f.y);
    ts[(nseg + k * 4 + 2) * 72 + cl] = f2bf(f.z);
    ts[(nseg + k * 4 + 3) * 72 + cl] = f2bf(f.w);
  }
  __syncthreads();
  const int nl = t >> 2, cseg = (t & 3) * 16;
  int4 a0 = *(int4*)&ts[nl * 72 + cseg];
  int4 a1 = *(int4*)&ts[nl * 72 + cseg + 8];
  unsigned short* dst = xT + ((size_t)b * N_ + n0 + nl) * C_ + c0 + cseg;
  *(int4*)dst = a0; *(int4*)(dst + 8) = a1;
}

// ---------------------------------------------------------------------------
// K0b: convert wq/wk/wv fp32 -> wb bf16 [1024][512] (q rows 0-255, k 256-511, v 512-1023)
// ---------------------------------------------------------------------------
__global__ __launch_bounds__(256) void k_wb(const float* __restrict__ wq,
                                            const float* __restrict__ wk,
                                            const float* __restrict__ wv,
                                            unsigned short* __restrict__ wb) {
  int e = (blockIdx.x * 256 + threadIdx.x) * 4;
  int row = e >> 9, col = e & 511;
  const float* src = (row < 256) ? &wq[row * 512 + col]
                   : (row < 512) ? &wk[(row - 256) * 512 + col]
                                 : &wv[(row - 512) * 512 + col];
  float4 f = *(const float4*)src;
  ushort4 o = { f2bf(f.x), f2bf(f.y), f2bf(f.z), f2bf(f.w) };
  *(ushort4*)&wb[e] = o;
}

// ---------------------------------------------------------------------------
// K1: QKV conv via MFMA. y[o][n] = sum_c W[o][c] x[c][n] + b[o].
// A = wb [o][c] frags, B = xT [n][c] frags. 64o x 64n tile, 256 thr, 4 waves.
// q/k outputs written TRANSPOSED bf16 (qT/kT [n][o]) via LDS; v natural [c][n].
// ---------------------------------------------------------------------------
__global__ __launch_bounds__(256) void k_qkv(
    const unsigned short* __restrict__ wb, const unsigned short* __restrict__ xT,
    const float* __restrict__ bq, const float* __restrict__ bk, const float* __restrict__ bv,
    unsigned short* __restrict__ qT, unsigned short* __restrict__ kT,
    unsigned short* __restrict__ vbf) {
  const int b = blockIdx.z, o0 = blockIdx.y * 64, n0 = blockIdx.x * 64;
  const int t = threadIdx.x, wave = t >> 6, lane = t & 63;
  const int la = lane & 15, quad = lane >> 4;
  const int ow = wave & 1, nw = wave >> 1;
  const unsigned short* xTb = xT + (size_t)b * N_ * C_;
  __shared__ unsigned short tp[64 * 72];  // [n][o] for q/k transpose

  v4f acc[2][2];
#pragma unroll
  for (int i = 0; i < 2; ++i)
#pragma unroll
    for (int j = 0; j < 2; ++j) acc[i][j] = (v4f){0.f, 0.f, 0.f, 0.f};

  const size_t arow0 = (size_t)(o0 + ow * 32 + la) * 512;
  const size_t brow0 = (size_t)(n0 + nw * 32 + la) * 512;
#pragma unroll 4
  for (int s = 0; s < 16; ++s) {
    const int kof = s * 32 + quad * 8;
    v8s a0 = ld8(&wb[arow0 + kof]);
    v8s a1 = ld8(&wb[arow0 + 16 * 512 + kof]);
    v8s b0 = ld8(&xTb[brow0 + kof]);
    v8s b1 = ld8(&xTb[brow0 + 16 * 512 + kof]);
    acc[0][0] = mfma16(a0, b0, acc[0][0]);
    acc[0][1] = mfma16(a0, b1, acc[0][1]);
    acc[1][0] = mfma16(a1, b0, acc[1][0]);
    acc[1][1] = mfma16(a1, b1, acc[1][1]);
  }

  if (o0 >= 512) {
    // v branch: natural [c][n] bf16 stores
#pragma unroll
    for (int i = 0; i < 2; ++i)
#pragma unroll
      for (int j = 0; j < 2; ++j)
#pragma unroll
        for (int r = 0; r < 4; ++r) {
          int og = o0 + ow * 32 + i * 16 + quad * 4 + r;
          int ng = n0 + nw * 32 + j * 16 + la;
          float v = acc[i][j][r] + bv[og - 512];
          vbf[((size_t)b * C_ + og - 512) * N_ + ng] = f2bf(v);
        }
  } else {
    const float* bias = (o0 < 256) ? bq : bk;
    const int obase = (o0 < 256) ? 0 : 256;
#pragma unroll
    for (int i = 0; i < 2; ++i)
#pragma unroll
      for (int j = 0; j < 2; ++j)
#pragma unroll
        for (int r = 0; r < 4; ++r) {
          int ol = ow * 32 + i * 16 + quad * 4 + r;
          int nl = nw * 32 + j * 16 + la;
          float v = acc[i][j][r] + bias[o0 - obase + ol];
          tp[nl * 72 + ol] = f2bf(v);
        }
    __syncthreads();
    const int nl = t >> 2, oseg = (t & 3) * 16;
    int4 a0 = *(int4*)&tp[nl * 72 + oseg];
    int4 a1 = *(int4*)&tp[nl * 72 + oseg + 8];
    unsigned short* dst = ((o0 < 256) ? qT : kT)
        + ((size_t)b * N_ + n0 + nl) * CI_ + (o0 & 255) + oseg;
    *(int4*)dst = a0; *(int4*)(dst + 8) = a1;
  }
}

// ---------------------------------------------------------------------------
// K2: fused PAM, flash-style with FIXED shift (no online max).
// block = 512 thr (8 waves), i-tile 64, j-tile 64, grid (64, B).
// S-phase: wave w -> i-subtiles {2ih,2ih+1} (ih=w&1), j-subtile jq=w>>1.
// PV-phase: wave w -> c-range [w*64, w*64+64).
// sa = tanh(gamma*acc/(l*N) + x), written fp32 + bf16.
// ---------------------------------------------------------------------------
__global__ __launch_bounds__(512, 2) void k_pam(
    const unsigned short* __restrict__ qT, const unsigned short* __restrict__ kT,
    const unsigned short* __restrict__ vbf, const float* __restrict__ x,
    const float* __restrict__ gamma_pam,
    float* __restrict__ sa, unsigned short* __restrict__ sabf) {
  const int b = blockIdx.y, i0 = blockIdx.x * 64;
  const int t = threadIdx.x, wave = t >> 6, lane = t & 63;
  const int la = lane & 15, quad = lane >> 4;
  const int ih = wave & 1, jq = wave >> 1;
  const int cb = wave * 64;

  __shared__ unsigned short pa[64 * 72];  // P bf16 [i][j], row stride 72
  __shared__ float l_lds[64];
  if (t < 64) l_lds[t] = 0.f;

  const unsigned short* qTb = qT + (size_t)b * N_ * CI_;
  const unsigned short* kTb = kT + (size_t)b * N_ * CI_;
  const unsigned short* vb  = vbf + (size_t)b * C_ * N_;

  // Q A-frags, register-resident across the whole j-loop
  v8s qf[2][8];
#pragma unroll
  for (int tt = 0; tt < 2; ++tt)
#pragma unroll
    for (int s = 0; s < 8; ++s)
      qf[tt][s] = ld8(&qTb[(size_t)(i0 + (2 * ih + tt) * 16 + la) * CI_ + s * 32 + quad * 8]);

  v4f acc[4][4];
#pragma unroll
  for (int ct = 0; ct < 4; ++ct)
#pragma unroll
    for (int it = 0; it < 4; ++it) acc[ct][it] = (v4f){0.f, 0.f, 0.f, 0.f};
  float lsum[2][4] = {};

  for (int j0 = 0; j0 < N_; j0 += 64) {
    // ---- S = Q^T K on this 64x64-j tile (wave computes 2 16x16 D-tiles) ----
    v8s kf[8];
#pragma unroll
    for (int s = 0; s < 8; ++s)
      kf[s] = ld8(&kTb[(size_t)(j0 + jq * 16 + la) * CI_ + s * 32 + quad * 8]);
    v4f s0 = (v4f){0.f, 0.f, 0.f, 0.f}, s1 = s0;
#pragma unroll
    for (int s = 0; s < 8; ++s) {
      s0 = mfma16(qf[0][s], kf[s], s0);
      s1 = mfma16(qf[1][s], kf[s], s1);
    }
    // ---- prefetch V frags for this j-tile ----
    v8s vf[4][2];
#pragma unroll
    for (int ct = 0; ct < 4; ++ct)
#pragma unroll
      for (int ks = 0; ks < 2; ++ks)
        vf[ct][ks] = ld8(&vb[(size_t)(cb + ct * 16 + la) * N_ + j0 + ks * 32 + quad * 8]);
    // ---- P = exp(S*scale - shift), write bf16 to LDS [i][j] ----
#pragma unroll
    for (int r = 0; r < 4; ++r) {
      float p0 = __expf(s0[r] * SCALE_PAM - SHIFT_PAM);
      float p1 = __expf(s1[r] * SCALE_PAM - SHIFT_PAM);
      pa[((2 * ih + 0) * 16 + quad * 4 + r) * 72 + jq * 16 + la] = f2bf(p0);
      pa[((2 * ih + 1) * 16 + quad * 4 + r) * 72 + jq * 16 + la] = f2bf(p1);
      lsum[0][r] += p0; lsum[1][r] += p1;
    }
    __syncthreads();
    // ---- PV: acc[c][i] += V[c][j] P^T[j][i] ----
#pragma unroll
    for (int it = 0; it < 4; ++it)
#pragma unroll
      for (int ks = 0; ks < 2; ++ks) {
        v8s pf; *(int4*)&pf = *(int4*)&pa[(it * 16 + la) * 72 + ks * 32 + quad * 8];
#pragma unroll
        for (int ct = 0; ct < 4; ++ct)
          acc[ct][it] = mfma16(vf[ct][ks], pf, acc[ct][it]);
      }
    __syncthreads();
  }

  // ---- reduce l per i-row ----
#pragma unroll
  for (int tt = 0; tt < 2; ++tt)
#pragma unroll
    for (int r = 0; r < 4; ++r) {
      float v = lsum[tt][r];
      v += __shfl_xor(v, 1); v += __shfl_xor(v, 2);
      v += __shfl_xor(v, 4); v += __shfl_xor(v, 8);
      if (la == 0) atomicAdd(&l_lds[(2 * ih + tt) * 16 + quad * 4 + r], v);
    }
  __syncthreads();

  // ---- epilogue: sa = tanh(gp * acc/(l*N) + x) ----
  const float gpv = gamma_pam[0];
  float linv[4];
#pragma unroll
  for (int it = 0; it < 4; ++it)
    linv[it] = 1.0f / (l_lds[it * 16 + la] * (float)N_);
#pragma unroll
  for (int ct = 0; ct < 4; ++ct)
#pragma unroll
    for (int it = 0; it < 4; ++it)
#pragma unroll
      for (int r = 0; r < 4; ++r) {
        int c = cb + ct * 16 + quad * 4 + r;
        size_t gi = ((size_t)(b * C_ + c)) * N_ + i0 + it * 16 + la;
        float pam = acc[ct][it][r] * linv[it];
        float sv = tanhf(fmaf(gpv, pam, x[gi]));
        sa[gi] = sv;
        sabf[gi] = f2bf(sv);
      }
}

// ---------------------------------------------------------------------------
// K_tr: transpose sa_bf [c][n] -> saT [n][c] (bf16), 64x64 tiles.
// ---------------------------------------------------------------------------
__global__ __launch_bounds__(256) void k_tr(const unsigned short* __restrict__ sabf,
                                            unsigned short* __restrict__ saT) {
  const int b = blockIdx.z, c0 = blockIdx.y * 64, n0 = blockIdx.x * 64;
  const int t = threadIdx.x;
  __shared__ unsigned short ts[64 * 72];
  const int cl = t >> 2, nseg = (t & 3) * 16;
  const unsigned short* src = sabf + ((size_t)b * C_ + c0 + cl) * N_ + n0 + nseg;
  ushort4 u[4];
#pragma unroll
  for (int k = 0; k < 4; ++k) u[k] = *(const ushort4*)(src + k * 4);
#pragma unroll
  for (int k = 0; k < 4; ++k) {
    ts[(nseg + k * 4 + 0) * 72 + cl] = u[k].x;
    ts[(nseg + k * 4 + 1) * 72 + cl] = u[k].y;
    ts[(nseg + k * 4 + 2) * 72 + cl] = u[k].z;
    ts[(nseg + k * 4 + 3) * 72 + cl] = u[k].w;
  }
  __syncthreads();
  const int nl = t >> 2, cseg = (t & 3) * 16;
  int4 a0 = *(int4*)&ts[nl * 72 + cseg];
  int4 a1 = *(int4*)&ts[nl * 72 + cseg + 8];
  unsigned short* dst = saT + ((size_t)b * N_ + n0 + nl) * C_ + c0 + cseg;
  *(int4*)dst = a0; *(int4*)(dst + 8) = a1;
}

// ---------------------------------------------------------------------------
// K3: CAM gram via MFMA, K-split 4. e_part[ks][b][c][d] = scale * sum sa_c sa_d
// A = sa_bf[c][n] frags, B = sa_bf[d][n] frags (transpose-symmetric layouts).
// ---------------------------------------------------------------------------
__global__ __launch_bounds__(256) void k_cam_e(const unsigned short* __restrict__ sabf,
                                               float* __restrict__ e_part) {
  const int b = blockIdx.z, ks = blockIdx.y;
  const int c0 = (blockIdx.x & 7) * 64, d0 = (blockIdx.x >> 3) * 64;
  const int t = threadIdx.x, wave = t >> 6, lane = t & 63;
  const int la = lane & 15, quad = lane >> 4;
  const int cw = wave & 1, dw = wave >> 1;
  const unsigned short* sb = sabf + (size_t)b * C_ * N_;

  v4f acc[2][2];
#pragma unroll
  for (int i = 0; i < 2; ++i)
#pragma unroll
    for (int j = 0; j < 2; ++j) acc[i][j] = (v4f){0.f, 0.f, 0.f, 0.f};

  const size_t ar0 = (size_t)(c0 + cw * 32 + la) * N_;
  const size_t br0 = (size_t)(d0 + dw * 32 + la) * N_;
#pragma unroll 4
  for (int s = 0; s < 32; ++s) {
    const int kof = ks * 1024 + s * 32 + quad * 8;
    v8s a0 = ld8(&sb[ar0 + kof]);
    v8s a1 = ld8(&sb[ar0 + (size_t)16 * N_ + kof]);
    v8s b0 = ld8(&sb[br0 + kof]);
    v8s b1 = ld8(&sb[br0 + (size_t)16 * N_ + kof]);
    acc[0][0] = mfma16(a0, b0, acc[0][0]);
    acc[0][1] = mfma16(a0, b1, acc[0][1]);
    acc[1][0] = mfma16(a1, b0, acc[1][0]);
    acc[1][1] = mfma16(a1, b1, acc[1][1]);
  }
  float* ep = e_part + ((size_t)(ks * B_ + b)) * C_ * C_;
#pragma unroll
  for (int i = 0; i < 2; ++i)
#pragma unroll
    for (int j = 0; j < 2; ++j)
#pragma unroll
      for (int r = 0; r < 4; ++r) {
        int c = c0 + cw * 32 + i * 16 + quad * 4 + r;
        int d = d0 + dw * 32 + j * 16 + la;
        ep[(size_t)c * C_ + d] = acc[i][j][r] * SCALE_CAM;
      }
}

// ---------------------------------------------------------------------------
// K4: CAM softmax (min-trick), sums 4 K-split parts, writes attn bf16 (/C folded).
// ---------------------------------------------------------------------------
__global__ __launch_bounds__(64) void k_cam_softmax(const float* __restrict__ e_part,
                                                    unsigned short* __restrict__ attnb) {
  const int c = blockIdx.x, b = blockIdx.y, lane = threadIdx.x;
  size_t roff = ((size_t)b * C_ + c) * C_;
  float vals[8];
#pragma unroll
  for (int r = 0; r < 8; ++r) {
    int d = lane + r * 64;
    float s = 0.f;
#pragma unroll
    for (int p = 0; p < 4; ++p) s += e_part[(size_t)(p * B_) * C_ * C_ + roff + d];
    vals[r] = s;
  }
  float mn = vals[0];
#pragma unroll
  for (int r = 1; r < 8; ++r) mn = fminf(mn, vals[r]);
#pragma unroll
  for (int m = 32; m >= 1; m >>= 1) mn = fminf(mn, __shfl_xor(mn, m));
  float sum = 0.f;
#pragma unroll
  for (int r = 0; r < 8; ++r) { vals[r] = __expf(mn - vals[r]); sum += vals[r]; }
#pragma unroll
  for (int m = 32; m >= 1; m >>= 1) sum += __shfl_xor(sum, m);
  float sc = (1.0f / (float)C_) / sum;
#pragma unroll
  for (int r = 0; r < 8; ++r) attnb[roff + lane + r * 64] = f2bf(vals[r] * sc);
}

// ---------------------------------------------------------------------------
// K5: out = gamma_cam * (attn @ sa) + sa.  A = attn bf16 [c][d], B = saT [n][d].
// ---------------------------------------------------------------------------
__global__ __launch_bounds__(256) void k_cam_out(
    const unsigned short* __restrict__ attnb, const unsigned short* __restrict__ saT,
    const float* __restrict__ sa, const float* __restrict__ gamma_cam,
    float* __restrict__ out) {
  const int b = blockIdx.z, c0 = blockIdx.y * 64, n0 = blockIdx.x * 64;
  const int t = threadIdx.x, wave = t >> 6, lane = t & 63;
  const int la = lane & 15, quad = lane >> 4;
  const int cw = wave & 1, nw = wave >> 1;
  const unsigned short* ab = attnb + (size_t)b * C_ * C_;
  const unsigned short* sTb = saT + (size_t)b * N_ * C_;

  v4f acc[2][2];
#pragma unroll
  for (int i = 0; i < 2; ++i)
#pragma unroll
    for (int j = 0; j < 2; ++j) acc[i][j] = (v4f){0.f, 0.f, 0.f, 0.f};

  const size_t ar0 = (size_t)(c0 + cw * 32 + la) * C_;
  const size_t br0 = (size_t)(n0 + nw * 32 + la) * C_;
#pragma unroll 4
  for (int s = 0; s < 16; ++s) {
    const int kof = s * 32 + quad * 8;
    v8s a0 = ld8(&ab[ar0 + kof]);
    v8s a1 = ld8(&ab[ar0 + 16 * C_ + kof]);
    v8s b0 = ld8(&sTb[br0 + kof]);
    v8s b1 = ld8(&sTb[br0 + 16 * C_ + kof]);
    acc[0][0] = mfma16(a0, b0, acc[0][0]);
    acc[0][1] = mfma16(a0, b1, acc[0][1]);
    acc[1][0] = mfma16(a1, b0, acc[1][0]);
    acc[1][1] = mfma16(a1, b1, acc[1][1]);
  }
  const float gc = gamma_cam[0];
#pragma unroll
  for (int i = 0; i < 2; ++i)
#pragma unroll
    for (int j = 0; j < 2; ++j)
#pragma unroll
      for (int r = 0; r < 4; ++r) {
        int c = c0 + cw * 32 + i * 16 + quad * 4 + r;
        int n = n0 + nw * 32 + j * 16 + la;
        size_t gi = ((size_t)(b * C_ + c)) * N_ + n;
        out[gi] = fmaf(gc, acc[i][j][r], sa[gi]);
      }
}

// ---------------------------------------------------------------------------
extern "C" void kernel_launch(void* const* d_in, const int* in_sizes, int n_in,
                              void* d_out, int out_size, void* d_ws, size_t ws_size,
                              hipStream_t stream) {
  const float* x  = (const float*)d_in[0];
  const float* wq = (const float*)d_in[1];
  const float* bq = (const float*)d_in[2];
  const float* wk = (const float*)d_in[3];
  const float* bk = (const float*)d_in[4];
  const float* wv = (const float*)d_in[5];
  const float* bv = (const float*)d_in[6];
  const float* gp = (const float*)d_in[7];
  const float* gc = (const float*)d_in[8];
  float* out = (float*)d_out;

  char* ws = (char*)d_ws;
  unsigned short* qT   = (unsigned short*)(ws);                         // 8.39 MB
  unsigned short* kT   = (unsigned short*)(ws + 8388608);               // 8.39 MB
  unsigned short* vbf  = (unsigned short*)(ws + 16777216);              // 16.78 MB
  unsigned short* xT   = (unsigned short*)(ws + 33554432);              // 16.78 MB
  unsigned short* wb   = (unsigned short*)(ws + 50331648);              // 1.05 MB
  float*          saf  = (float*)(ws + 51380224);                       // 33.55 MB
  unsigned short* sabf = (unsigned short*)(ws + 84934656);              // 16.78 MB
  unsigned short* saT  = (unsigned short*)(ws + 101711872);             // 16.78 MB
  float*          ep   = (float*)(ws + 118489088);                      // 16.78 MB
  unsigned short* atb  = (unsigned short*)(ws + 135266304);             // 2.10 MB
  // total ~137.4 MB

  k_xT<<<dim3(64, 8, B_), 256, 0, stream>>>(x, xT);
  k_wb<<<dim3(512), 256, 0, stream>>>(wq, wk, wv, wb);
  k_qkv<<<dim3(64, 16, B_), 256, 0, stream>>>(wb, xT, bq, bk, bv, qT, kT, vbf);
  k_pam<<<dim3(64, B_), 512, 0, stream>>>(qT, kT, vbf, x, gp, saf, sabf);
  k_tr<<<dim3(64, 8, B_), 256, 0, stream>>>(sabf, saT);
  k_cam_e<<<dim3(64, 4, B_), 256, 0, stream>>>(sabf, ep);
  k_cam_softmax<<<dim3(C_, B_), 64, 0, stream>>>(ep, atb);
  k_cam_out<<<dim3(64, 8, B_), 256, 0, stream>>>(atb, saT, saf, gc, out);
}